// Round 6
// baseline (280.825 us; speedup 1.0000x reference)
//
#include <hip/hip_runtime.h>
#include <cstdint>

// ============================================================================
// Dual-source attention, MI355X. sen/W2 dead (softmax shift invariance).
// Round-5: attn QBLK=128 (4 blocks/CU, 4 waves/SIMD for MFMA/VALU overlap),
// setprio around MFMA clusters; GEMM epilogue restructured through LDS for
// coalesced 16B stores (was 64 scalar 2B stores/thread).
// ============================================================================

typedef __bf16 bf16x8 __attribute__((ext_vector_type(8)));
typedef __bf16 bf16x4 __attribute__((ext_vector_type(4)));
typedef float  f32x4  __attribute__((ext_vector_type(4)));
typedef float  f32x16 __attribute__((ext_vector_type(16)));
typedef unsigned int u32x4 __attribute__((ext_vector_type(4)));

#define MFMA16(a,b,c) __builtin_amdgcn_mfma_f32_16x16x32_bf16(a,b,c,0,0,0)
#define MFMA32(a,b,c) __builtin_amdgcn_mfma_f32_32x32x16_bf16(a,b,c,0,0,0)

static __device__ __forceinline__ float exp2_raw(float x) {
    float r; asm("v_exp_f32 %0, %1" : "=v"(r) : "v"(x)); return r;
}
static __device__ __forceinline__ uint32_t pkbf16(float a, float b) {
    uint32_t r; asm("v_cvt_pk_bf16_f32 %0, %1, %2" : "=v"(r) : "v"(a), "v"(b)); return r;
}
static __device__ __forceinline__ void lds_fence() {
    asm volatile("s_waitcnt lgkmcnt(0)" ::: "memory");
    __builtin_amdgcn_sched_barrier(0);
}
static __device__ __forceinline__ f32x16 zero16() {
    f32x16 z;
#pragma unroll
    for (int i = 0; i < 16; ++i) z[i] = 0.f;
    return z;
}
static __device__ __forceinline__ bf16x8 zero8() {
    return __builtin_bit_cast(bf16x8, (u32x4){0u, 0u, 0u, 0u});
}

#define GLLDS(src, dst)                                                        \
    __builtin_amdgcn_global_load_lds(                                          \
        (const __attribute__((address_space(1))) void*)(src),                  \
        (__attribute__((address_space(3))) void*)(dst), 16, 0, 0)

static constexpr float QSCALE = 0.12751879523486166f;  // (2*64)^-0.5 * log2(e)

// ---------------------------------------------------------------------------
__global__ __launch_bounds__(256) void k_cvt_tok(const float* __restrict__ in,
                                                 __bf16* __restrict__ out) {
    int i = (blockIdx.x * 256 + threadIdx.x) * 4;
    float4 v = *(const float4*)&in[i];
    bf16x4 o = {(__bf16)v.x, (__bf16)v.y, (__bf16)v.z, (__bf16)v.w};
    *(bf16x4*)&out[i] = o;
}

// ---------------------------------------------------------------------------
__global__ __launch_bounds__(256) void k_w1t(const float* __restrict__ W1,
                                             __bf16* __restrict__ W1T) {
    __shared__ float t[32][33];
    int bx = blockIdx.x % 96, by = blockIdx.x / 96;
    int r0 = by * 32, c0 = bx * 32;
    int tr = threadIdx.x >> 3, tc = (threadIdx.x & 7) * 4;
    float4 v = *(const float4*)&W1[(size_t)(r0 + tr) * 3072 + c0 + tc];
    t[tr][tc + 0] = v.x; t[tr][tc + 1] = v.y; t[tr][tc + 2] = v.z; t[tr][tc + 3] = v.w;
    __syncthreads();
    bf16x4 o = {(__bf16)t[tc + 0][tr], (__bf16)t[tc + 1][tr],
                (__bf16)t[tc + 2][tr], (__bf16)t[tc + 3][tr]};
    *(bf16x4*)&W1T[(size_t)(c0 + tr) * 1024 + r0 + tc] = o;
}

// ---------------------------------------------------------------------------
// mask -> flag bf16 (orig order, for V-zeroing) + slot-permuted flagp (for
// the denominator MFMA A-row).  slot = {k[4:3], k[2], k[5], k[1:0]}.
__global__ __launch_bounds__(256) void k_mask(const int* __restrict__ m,
                                              __bf16* __restrict__ fl,
                                              __bf16* __restrict__ flp) {
    int i = blockIdx.x * 256 + threadIdx.x;
    fl[i] = (__bf16)(float)m[i];
    int s6 = i & 63;
    int kp = ((s6 >> 2) & 1) * 32 + ((s6 >> 4) & 3) * 8 + ((s6 >> 3) & 1) * 4 + (s6 & 3);
    flp[i] = (__bf16)(float)m[(i & ~63) | kp];
}

// ---------------------------------------------------------------------------
// GEMM C[8192][3072] = A @ W1 (BT pre-transposed). 128x128 tile, BK=32,
// double-buffered global_load_lds staging. n-blocks are stream-pure
// (128 | 1024): tn 0-7 -> Q, 8-15 -> K, 16-23 -> V^T (slot-permuted).
// Q/K epilogue: acc -> bf16 into LDS [128][136-pitch], then 8x16B coalesced
// global stores per thread (replaces 64 scalar 2B stores).
// ---------------------------------------------------------------------------
__global__ __launch_bounds__(256) void k_gemm_qkv(const __bf16* __restrict__ A,
                                                  const __bf16* __restrict__ BT,
                                                  const __bf16* __restrict__ FLAG,
                                                  __bf16* __restrict__ Q,
                                                  __bf16* __restrict__ K,
                                                  __bf16* __restrict__ VT) {
    __shared__ __align__(16) char gsm[34816];  // staging 2x16KB; epi 128x272B
    const int tid = threadIdx.x;
    const int bid = blockIdx.x;
    const int sw = (bid & 7) * 192 + (bid >> 3);  // XCD-chunked (1536 % 8 == 0)
    const int tm = sw / 24, tn = sw % 24;
    const int m0 = tm * 128, n0 = tn * 128;
    const int l = tid & 63, wv = tid >> 6;
    const int l15 = l & 15, l4 = l >> 4;
    const int wr = wv >> 1, wc = wv & 1;

    const char* Ab = (const char*)A;
    const char* Bb = (const char*)BT;
    const size_t aoff = (size_t)(m0 + wv * 32 + (l >> 2)) * 2048 + (l & 3) * 16;
    const size_t boff = (size_t)(n0 + wv * 32 + (l >> 2)) * 2048 + (l & 3) * 16;

    f32x4 acc[4][4];
#pragma unroll
    for (int i = 0; i < 4; ++i)
#pragma unroll
        for (int j = 0; j < 4; ++j) acc[i][j] = (f32x4){0.f, 0.f, 0.f, 0.f};

    auto STAGE = [&](int nb, int kt) {
        char* ab = gsm + nb * 16384 + wv * 2048;
        char* bb = ab + 8192;
#pragma unroll
        for (int i = 0; i < 2; ++i) {
            GLLDS(Ab + aoff + (size_t)i * 32768 + (size_t)kt * 64, ab + i * 1024);
            GLLDS(Bb + boff + (size_t)i * 32768 + (size_t)kt * 64, bb + i * 1024);
        }
    };
    STAGE(0, 0);

    for (int kt = 0; kt < 32; ++kt) {
        const int cur = kt & 1;
        __syncthreads();                    // buf[cur] staged; prev reads done
        if (kt < 31) STAGE(cur ^ 1, kt + 1);  // hidden under this tile's MFMA
        const char* As = gsm + cur * 16384;
        const char* Bs = As + 8192;

        bf16x8 af[4], bb[4];
#pragma unroll
        for (int mi = 0; mi < 4; ++mi)
            af[mi] = *(const bf16x8*)(As + (wr * 64 + mi * 16 + l15) * 64 + l4 * 16);
#pragma unroll
        for (int ni = 0; ni < 4; ++ni)
            bb[ni] = *(const bf16x8*)(Bs + (wc * 64 + ni * 16 + l15) * 64 + l4 * 16);
#pragma unroll
        for (int mi = 0; mi < 4; ++mi)
#pragma unroll
            for (int ni = 0; ni < 4; ++ni)
                acc[mi][ni] = MFMA16(af[mi], bb[ni], acc[mi][ni]);
    }

    __syncthreads();  // staging buffers dead; LDS reusable for epilogue

    // D-frag: row = (l>>4)*4 + r, col = l&15.
    if (tn < 16) {
        // ---- Q/K: stage bf16 tile in LDS (pitch 272B = 16-aligned, odd*16) ----
        const float scl = (tn < 8) ? QSCALE : 1.0f;
        char* csm = gsm;
#pragma unroll
        for (int mi = 0; mi < 4; ++mi) {
            const int row = wr * 64 + mi * 16 + l4 * 4;
#pragma unroll
            for (int ni = 0; ni < 4; ++ni) {
                const int col = wc * 64 + ni * 16 + l15;
#pragma unroll
                for (int r = 0; r < 4; ++r)
                    *(__bf16*)(csm + (row + r) * 272 + col * 2) =
                        (__bf16)(acc[mi][ni][r] * scl);
            }
        }
        __syncthreads();
        const int row = tid >> 1, hh = tid & 1;
        const int rowg = m0 + row;
        const int b = rowg >> 11, n = rowg & 2047;
        const int h = ((n0 & 1023) >> 6) + hh;
        __bf16* dst = ((tn < 8) ? Q : K) + ((size_t)(b * 16 + h) * 2048 + n) * 64;
#pragma unroll
        for (int j = 0; j < 8; ++j)
            *(uint4*)(dst + j * 8) = *(const uint4*)(csm + row * 272 + hh * 128 + j * 16);
    } else {
        // ---- V: flag-zeroed, transposed + slot-permuted, bf16x4 stores ----
#pragma unroll
        for (int mi = 0; mi < 4; ++mi) {
            const int rowb = m0 + wr * 64 + mi * 16 + l4 * 4;
            const int b = rowb >> 11, n = rowb & 2047;
            const bf16x4 fv = *(const bf16x4*)&FLAG[b * 2048 + n];
#pragma unroll
            for (int ni = 0; ni < 4; ++ni) {
                const int col = n0 + wc * 64 + ni * 16 + l15;
                const int cc = col & 1023;
                const int h = cc >> 6, d = cc & 63;
                bf16x4 pv = {(__bf16)(acc[mi][ni][0] * (float)fv[0]),
                             (__bf16)(acc[mi][ni][1] * (float)fv[1]),
                             (__bf16)(acc[mi][ni][2] * (float)fv[2]),
                             (__bf16)(acc[mi][ni][3] * (float)fv[3])};
                const int k6 = n & 63;  // low 2 bits 0; r appends slot[1:0]
                const int nsl = (n & ~63) | (((k6 >> 3) & 3) << 4) |
                                (((k6 >> 2) & 1) << 3) | ((k6 >> 5) << 2);
                *(bf16x4*)&VT[((size_t)(b * 16 + h) * 64 + d) * 2048 + nsl] = pv;
            }
        }
    }
}

// ---------------------------------------------------------------------------
// Flash attention, 32x32x16 MFMA. QBLK=128: 64 bh x 16 qtiles = 1024 blocks
// (4/CU -> 4 waves/SIMD), 4 waves x 32 q-rows, 64-key tiles. d-chunked
// conflict-free LDS K/V (double-buffered, 1 barrier/tile). S^T = K·Q^T;
// P-frags in-register via cvt_pk (slot-permuted V); flag-row MFMA denom;
// defer-max; setprio around MFMA clusters (T5).
// ---------------------------------------------------------------------------
__global__ __launch_bounds__(256, 4) void k_attn(const __bf16* __restrict__ Q,
                                                 const __bf16* __restrict__ K,
                                                 const __bf16* __restrict__ VT,
                                                 const __bf16* __restrict__ FLAGP,
                                                 float* __restrict__ out) {
    __shared__ __align__(16) char smem[33280];  // 2x16KB staging; epi overlay
    const int tid = threadIdx.x;
    const int bid = blockIdx.x;
    const int swz = (bid & 7) * 128 + (bid >> 3);  // 1024 = 8*128; 8bh/XCD = 4MB L2 set
    const int bh = swz >> 4, qt = swz & 15;
    const int b = bh >> 4, h = bh & 15;
    const int wv = tid >> 6, l = tid & 63, l31 = l & 31, hi = l >> 5;

    const char* Kg = (const char*)K + (size_t)bh * 2048 * 128;
    const char* Vg = (const char*)VT + (size_t)bh * 64 * 4096;
    const __bf16* Fg = FLAGP + b * 2048;

    // Q fragments (pre-scaled by QSCALE): B-operand, col = q
    const __bf16* qp = Q + ((size_t)bh * 2048 + qt * 128 + wv * 32 + l31) * 64;
    bf16x8 qf[4];
#pragma unroll
    for (int m = 0; m < 4; ++m) qf[m] = *(const bf16x8*)(qp + m * 16 + hi * 8);

    f32x16 o0 = zero16(), o1 = zero16(), fa = zero16();
    float mr = -1e30f;

    auto STAGE = [&](int nb, int t) {
        char* base = smem + nb * 16384;
#pragma unroll
        for (int i = 0; i < 2; ++i) {
            const int blk = wv + i * 4;            // 0..7 (1KB chunks)
            const int mc = blk >> 1, rb = blk & 1;
            const int row = rb * 32 + (l >> 1);    // key row / d row
            GLLDS(Kg + (size_t)(t * 64 + row) * 128 + mc * 32 + (l & 1) * 16,
                  base + blk * 1024);
            GLLDS(Vg + (size_t)row * 4096 + t * 128 + mc * 32 + (l & 1) * 16,
                  base + 8192 + blk * 1024);
        }
    };
    STAGE(0, 0);

    for (int t = 0; t < 32; ++t) {
        const int cur = t & 1;
        __syncthreads();                      // buf[cur] ready; prev reads done
        if (t < 31) STAGE(cur ^ 1, t + 1);    // prefetch hides under compute
        const char* Ks = smem + cur * 16384;
        const char* Vs = Ks + 8192;

        // K fragments: A-operand, row = key slot (d-chunked, conflict-free)
        bf16x8 kf0[4], kf1[4];
#pragma unroll
        for (int m = 0; m < 4; ++m) {
            kf0[m] = *(const bf16x8*)(Ks + m * 2048 + l31 * 32 + hi * 16);
            kf1[m] = *(const bf16x8*)(Ks + m * 2048 + (32 + l31) * 32 + hi * 16);
        }

        // ---- QK^T (scores in exp2 domain) ----
        f32x16 s0 = zero16(), s1 = zero16();
        __builtin_amdgcn_s_setprio(1);
#pragma unroll
        for (int m = 0; m < 4; ++m) s0 = MFMA32(kf0[m], qf[m], s0);
#pragma unroll
        for (int m = 0; m < 4; ++m) s1 = MFMA32(kf1[m], qf[m], s1);
        __builtin_amdgcn_s_setprio(0);

        // ---- softmax: row max + defer-max rescale ----
        {
            float mx = fmaxf(s0[0], s1[0]);
#pragma unroll
            for (int i = 1; i < 16; ++i) mx = fmaxf(mx, fmaxf(s0[i], s1[i]));
            mx = fmaxf(mx, __shfl_xor(mx, 32, 64));
            if (!__all(mx <= mr + 8.0f)) {     // defer-max (T13)
                float mn = fmaxf(mr, mx);
                float al = exp2_raw(mr - mn);
                o0 *= al; o1 *= al; fa *= al; mr = mn;
            }
        }
        u32x4 pk[4];
#pragma unroll
        for (int m = 0; m < 4; ++m) {
            pk[m].x = pkbf16(exp2_raw(s0[4 * m] - mr), exp2_raw(s0[4 * m + 1] - mr));
            pk[m].y = pkbf16(exp2_raw(s0[4 * m + 2] - mr), exp2_raw(s0[4 * m + 3] - mr));
            pk[m].z = pkbf16(exp2_raw(s1[4 * m] - mr), exp2_raw(s1[4 * m + 1] - mr));
            pk[m].w = pkbf16(exp2_raw(s1[4 * m + 2] - mr), exp2_raw(s1[4 * m + 3] - mr));
        }

        // flag A-row (only l31==0 lanes carry data)
        bf16x8 ff[4];
#pragma unroll
        for (int m = 0; m < 4; ++m) ff[m] = zero8();
        if (l31 == 0) {
#pragma unroll
            for (int m = 0; m < 4; ++m)
                ff[m] = *(const bf16x8*)(Fg + t * 64 + m * 16 + hi * 8);
        }

        // ---- PV + denominator ----
        __builtin_amdgcn_s_setprio(1);
#pragma unroll
        for (int m = 0; m < 4; ++m) {
            bf16x8 vf0 = *(const bf16x8*)(Vs + m * 2048 + l31 * 32 + hi * 16);
            bf16x8 vf1 = *(const bf16x8*)(Vs + m * 2048 + (32 + l31) * 32 + hi * 16);
            bf16x8 p = __builtin_bit_cast(bf16x8, pk[m]);
            o0 = MFMA32(vf0, p, o0);
            o1 = MFMA32(vf1, p, o1);
            fa = MFMA32(ff[m], p, fa);
        }
        __builtin_amdgcn_s_setprio(0);
    }

    // ---- epilogue: denom = flag-acc row 0, transpose via LDS, store ----
    __syncthreads();
    float* osm = (float*)smem + wv * 2080;  // 32 x 65 f32 per wave
    const size_t obase = ((size_t)b * 2048 + qt * 128 + wv * 32) * 1024 + h * 64 + l;
    const float inv = 1.0f / __shfl(fa[0], l31, 64);
#pragma unroll
    for (int r = 0; r < 16; ++r) {
        const int d = (r & 3) + 8 * (r >> 2) + 4 * hi;
        osm[l31 * 65 + d] = o0[r] * inv;
        osm[l31 * 65 + d + 32] = o1[r] * inv;
    }
    lds_fence();
#pragma unroll
    for (int qi = 0; qi < 32; ++qi)
        out[obase + (size_t)qi * 1024] = osm[qi * 65 + l];
}

// ---------------------------------------------------------------------------
extern "C" void kernel_launch(void* const* d_in, const int* in_sizes, int n_in,
                              void* d_out, int out_size, void* d_ws, size_t ws_size,
                              hipStream_t stream) {
    const float* tokens = (const float*)d_in[0];
    // d_in[1] = sen : DEAD, d_in[3] = W2 : DEAD
    const float* W1 = (const float*)d_in[2];
    const int* mask = (const int*)d_in[4];
    float* out = (float*)d_out;

    char* w = (char*)d_ws;
    __bf16* tokbf = (__bf16*)(w + 0);           // 16,777,216 B
    __bf16* w1t   = (__bf16*)(w + 16777216);    //  6,291,456 B
    __bf16* qarr  = (__bf16*)(w + 23068672);    // 16,777,216 B
    __bf16* karr  = (__bf16*)(w + 39845888);    // 16,777,216 B
    __bf16* vtar  = (__bf16*)(w + 56623104);    // 16,777,216 B (slot-permuted)
    __bf16* flagb = (__bf16*)(w + 73400320);    //     16,384 B (orig order)
    __bf16* flagp = (__bf16*)(w + 73416704);    //     16,384 B (slot-permuted)

    k_cvt_tok<<<8192, 256, 0, stream>>>(tokens, tokbf);
    k_w1t<<<3072, 256, 0, stream>>>(W1, w1t);
    k_mask<<<32, 256, 0, stream>>>(mask, flagb, flagp);
    k_gemm_qkv<<<1536, 256, 0, stream>>>(tokbf, w1t, flagb, qarr, karr, vtar);
    k_attn<<<1024, 256, 0, stream>>>(qarr, karr, vtar, flagp, out);
}

// Round 8
// 269.380 us; speedup vs baseline: 1.0425x; 1.0425x over previous
//
#include <hip/hip_runtime.h>
#include <cstdint>

// ============================================================================
// Dual-source attention, MI355X. sen/W2 dead (softmax shift invariance).
// Round-8: revert to PROVEN defer-max numerics (round-4/6 passed at the
// bf16(V) rounding floor; round-7's no-max variant empirically failed 37x
// worse despite scale-invariance arguments -- mechanism unresolved, reverted).
// Kept from round-7: QBLK=256 geometry, setprio clusters, merged cvt+mask.
// ============================================================================

typedef __bf16 bf16x8 __attribute__((ext_vector_type(8)));
typedef __bf16 bf16x4 __attribute__((ext_vector_type(4)));
typedef float  f32x4  __attribute__((ext_vector_type(4)));
typedef float  f32x16 __attribute__((ext_vector_type(16)));
typedef unsigned int u32x4 __attribute__((ext_vector_type(4)));

#define MFMA16(a,b,c) __builtin_amdgcn_mfma_f32_16x16x32_bf16(a,b,c,0,0,0)
#define MFMA32(a,b,c) __builtin_amdgcn_mfma_f32_32x32x16_bf16(a,b,c,0,0,0)

static __device__ __forceinline__ float exp2_raw(float x) {
    float r; asm("v_exp_f32 %0, %1" : "=v"(r) : "v"(x)); return r;
}
static __device__ __forceinline__ uint32_t pkbf16(float a, float b) {
    uint32_t r; asm("v_cvt_pk_bf16_f32 %0, %1, %2" : "=v"(r) : "v"(a), "v"(b)); return r;
}
static __device__ __forceinline__ void lds_fence() {
    asm volatile("s_waitcnt lgkmcnt(0)" ::: "memory");
    __builtin_amdgcn_sched_barrier(0);
}
static __device__ __forceinline__ f32x16 zero16() {
    f32x16 z;
#pragma unroll
    for (int i = 0; i < 16; ++i) z[i] = 0.f;
    return z;
}
static __device__ __forceinline__ bf16x8 zero8() {
    return __builtin_bit_cast(bf16x8, (u32x4){0u, 0u, 0u, 0u});
}

#define GLLDS(src, dst)                                                        \
    __builtin_amdgcn_global_load_lds(                                          \
        (const __attribute__((address_space(1))) void*)(src),                  \
        (__attribute__((address_space(3))) void*)(dst), 16, 0, 0)

static constexpr float QSCALE = 0.12751879523486166f;  // (2*64)^-0.5 * log2(e)

// ---------------------------------------------------------------------------
// tokens f32 -> bf16; gi<8192 threads also build the mask flags (merged).
// ---------------------------------------------------------------------------
__global__ __launch_bounds__(256) void k_cvt_tok(const float* __restrict__ in,
                                                 const int* __restrict__ m,
                                                 __bf16* __restrict__ out,
                                                 __bf16* __restrict__ fl,
                                                 __bf16* __restrict__ flp) {
    int gi = blockIdx.x * 256 + threadIdx.x;
    int i = gi * 4;
    float4 v = *(const float4*)&in[i];
    bf16x4 o = {(__bf16)v.x, (__bf16)v.y, (__bf16)v.z, (__bf16)v.w};
    *(bf16x4*)&out[i] = o;
    if (gi < 8192) {
        fl[gi] = (__bf16)(float)m[gi];
        int s6 = gi & 63;
        int kp = ((s6 >> 2) & 1) * 32 + ((s6 >> 4) & 3) * 8 + ((s6 >> 3) & 1) * 4 + (s6 & 3);
        flp[gi] = (__bf16)(float)m[(gi & ~63) | kp];
    }
}

// ---------------------------------------------------------------------------
__global__ __launch_bounds__(256) void k_w1t(const float* __restrict__ W1,
                                             __bf16* __restrict__ W1T) {
    __shared__ float t[32][33];
    int bx = blockIdx.x % 96, by = blockIdx.x / 96;
    int r0 = by * 32, c0 = bx * 32;
    int tr = threadIdx.x >> 3, tc = (threadIdx.x & 7) * 4;
    float4 v = *(const float4*)&W1[(size_t)(r0 + tr) * 3072 + c0 + tc];
    t[tr][tc + 0] = v.x; t[tr][tc + 1] = v.y; t[tr][tc + 2] = v.z; t[tr][tc + 3] = v.w;
    __syncthreads();
    bf16x4 o = {(__bf16)t[tc + 0][tr], (__bf16)t[tc + 1][tr],
                (__bf16)t[tc + 2][tr], (__bf16)t[tc + 3][tr]};
    *(bf16x4*)&W1T[(size_t)(c0 + tr) * 1024 + r0 + tc] = o;
}

// ---------------------------------------------------------------------------
// GEMM C[8192][3072] = A @ W1 (BT pre-transposed). 128x128 tile, BK=32,
// double-buffered global_load_lds staging. tn 0-7 -> Q, 8-15 -> K,
// 16-23 -> V^T (slot-permuted). Q/K epilogue via LDS for 16B stores.
// ---------------------------------------------------------------------------
__global__ __launch_bounds__(256) void k_gemm_qkv(const __bf16* __restrict__ A,
                                                  const __bf16* __restrict__ BT,
                                                  const __bf16* __restrict__ FLAG,
                                                  __bf16* __restrict__ Q,
                                                  __bf16* __restrict__ K,
                                                  __bf16* __restrict__ VT) {
    __shared__ __align__(16) char gsm[34816];  // staging 2x16KB; epi 128x272B
    const int tid = threadIdx.x;
    const int bid = blockIdx.x;
    const int sw = (bid & 7) * 192 + (bid >> 3);  // XCD-chunked (1536 % 8 == 0)
    const int tm = sw / 24, tn = sw % 24;
    const int m0 = tm * 128, n0 = tn * 128;
    const int l = tid & 63, wv = tid >> 6;
    const int l15 = l & 15, l4 = l >> 4;
    const int wr = wv >> 1, wc = wv & 1;

    const char* Ab = (const char*)A;
    const char* Bb = (const char*)BT;
    const size_t aoff = (size_t)(m0 + wv * 32 + (l >> 2)) * 2048 + (l & 3) * 16;
    const size_t boff = (size_t)(n0 + wv * 32 + (l >> 2)) * 2048 + (l & 3) * 16;

    f32x4 acc[4][4];
#pragma unroll
    for (int i = 0; i < 4; ++i)
#pragma unroll
        for (int j = 0; j < 4; ++j) acc[i][j] = (f32x4){0.f, 0.f, 0.f, 0.f};

    auto STAGE = [&](int nb, int kt) {
        char* ab = gsm + nb * 16384 + wv * 2048;
        char* bb = ab + 8192;
#pragma unroll
        for (int i = 0; i < 2; ++i) {
            GLLDS(Ab + aoff + (size_t)i * 32768 + (size_t)kt * 64, ab + i * 1024);
            GLLDS(Bb + boff + (size_t)i * 32768 + (size_t)kt * 64, bb + i * 1024);
        }
    };
    STAGE(0, 0);

    for (int kt = 0; kt < 32; ++kt) {
        const int cur = kt & 1;
        __syncthreads();                    // buf[cur] staged; prev reads done
        if (kt < 31) STAGE(cur ^ 1, kt + 1);  // hidden under this tile's MFMA
        const char* As = gsm + cur * 16384;
        const char* Bs = As + 8192;

        bf16x8 af[4], bb[4];
#pragma unroll
        for (int mi = 0; mi < 4; ++mi)
            af[mi] = *(const bf16x8*)(As + (wr * 64 + mi * 16 + l15) * 64 + l4 * 16);
#pragma unroll
        for (int ni = 0; ni < 4; ++ni)
            bb[ni] = *(const bf16x8*)(Bs + (wc * 64 + ni * 16 + l15) * 64 + l4 * 16);
#pragma unroll
        for (int mi = 0; mi < 4; ++mi)
#pragma unroll
            for (int ni = 0; ni < 4; ++ni)
                acc[mi][ni] = MFMA16(af[mi], bb[ni], acc[mi][ni]);
    }

    __syncthreads();  // staging buffers dead; LDS reusable for epilogue

    // D-frag: row = (l>>4)*4 + r, col = l&15.
    if (tn < 16) {
        const float scl = (tn < 8) ? QSCALE : 1.0f;
        char* csm = gsm;
#pragma unroll
        for (int mi = 0; mi < 4; ++mi) {
            const int row = wr * 64 + mi * 16 + l4 * 4;
#pragma unroll
            for (int ni = 0; ni < 4; ++ni) {
                const int col = wc * 64 + ni * 16 + l15;
#pragma unroll
                for (int r = 0; r < 4; ++r)
                    *(__bf16*)(csm + (row + r) * 272 + col * 2) =
                        (__bf16)(acc[mi][ni][r] * scl);
            }
        }
        __syncthreads();
        const int row = tid >> 1, hh = tid & 1;
        const int rowg = m0 + row;
        const int b = rowg >> 11, n = rowg & 2047;
        const int h = ((n0 & 1023) >> 6) + hh;
        __bf16* dst = ((tn < 8) ? Q : K) + ((size_t)(b * 16 + h) * 2048 + n) * 64;
#pragma unroll
        for (int j = 0; j < 8; ++j)
            *(uint4*)(dst + j * 8) = *(const uint4*)(csm + row * 272 + hh * 128 + j * 16);
    } else {
        // ---- V: flag-zeroed, transposed + slot-permuted, bf16x4 stores ----
#pragma unroll
        for (int mi = 0; mi < 4; ++mi) {
            const int rowb = m0 + wr * 64 + mi * 16 + l4 * 4;
            const int b = rowb >> 11, n = rowb & 2047;
            const bf16x4 fv = *(const bf16x4*)&FLAG[b * 2048 + n];
#pragma unroll
            for (int ni = 0; ni < 4; ++ni) {
                const int col = n0 + wc * 64 + ni * 16 + l15;
                const int cc = col & 1023;
                const int h = cc >> 6, d = cc & 63;
                bf16x4 pv = {(__bf16)(acc[mi][ni][0] * (float)fv[0]),
                             (__bf16)(acc[mi][ni][1] * (float)fv[1]),
                             (__bf16)(acc[mi][ni][2] * (float)fv[2]),
                             (__bf16)(acc[mi][ni][3] * (float)fv[3])};
                const int k6 = n & 63;  // low 2 bits 0; r appends slot[1:0]
                const int nsl = (n & ~63) | (((k6 >> 3) & 3) << 4) |
                                (((k6 >> 2) & 1) << 3) | ((k6 >> 5) << 2);
                *(bf16x4*)&VT[((size_t)(b * 16 + h) * 64 + d) * 2048 + nsl] = pv;
            }
        }
    }
}

// ---------------------------------------------------------------------------
// Flash attention, 32x32x16 MFMA, QBLK=256 (512 blocks, 4 waves x 64 q,
// 2 coltiles sharing K/V frag reads). PROVEN defer-max softmax (T13, THR=8
// in exp2 domain): P = exp2(s - mr) <= 2^8. Denominator via flag-row MFMA;
// d-chunked conflict-free LDS, double-buffered, 1 barrier/tile; setprio (T5).
// ---------------------------------------------------------------------------
__global__ __launch_bounds__(256, 2) void k_attn(const __bf16* __restrict__ Q,
                                                 const __bf16* __restrict__ K,
                                                 const __bf16* __restrict__ VT,
                                                 const __bf16* __restrict__ FLAGP,
                                                 float* __restrict__ out) {
    __shared__ __align__(16) char smem[33280];  // 2x16KB staging; epi overlay
    const int tid = threadIdx.x;
    const int bid = blockIdx.x;
    const int swz = (bid & 7) * 64 + (bid >> 3);  // XCD-chunked (512 = 8*64)
    const int bh = swz >> 3, qt = swz & 7;
    const int b = bh >> 4, h = bh & 15;
    const int wv = tid >> 6, l = tid & 63, l31 = l & 31, hi = l >> 5;

    const char* Kg = (const char*)K + (size_t)bh * 2048 * 128;
    const char* Vg = (const char*)VT + (size_t)bh * 64 * 4096;
    const __bf16* Fg = FLAGP + b * 2048;

    // Q fragments (pre-scaled by QSCALE): B-operand, col = q
    const __bf16* qp = Q + ((size_t)bh * 2048 + qt * 256 + wv * 64 + l31) * 64;
    bf16x8 qf0[4], qf1[4];
#pragma unroll
    for (int m = 0; m < 4; ++m) {
        qf0[m] = *(const bf16x8*)(qp + m * 16 + hi * 8);
        qf1[m] = *(const bf16x8*)(qp + 32 * 64 + m * 16 + hi * 8);
    }

    f32x16 o00 = zero16(), o01 = zero16(), o10 = zero16(), o11 = zero16();
    f32x16 fa0 = zero16(), fa1 = zero16();
    float mr0 = -1e30f, mr1 = -1e30f;

    auto STAGE = [&](int nb, int t) {
        char* base = smem + nb * 16384;
#pragma unroll
        for (int i = 0; i < 2; ++i) {
            const int blk = wv + i * 4;            // 0..7 (1KB chunks)
            const int mc = blk >> 1, rb = blk & 1;
            const int row = rb * 32 + (l >> 1);    // key row / d row
            GLLDS(Kg + (size_t)(t * 64 + row) * 128 + mc * 32 + (l & 1) * 16,
                  base + blk * 1024);
            GLLDS(Vg + (size_t)row * 4096 + t * 128 + mc * 32 + (l & 1) * 16,
                  base + 8192 + blk * 1024);
        }
    };
    STAGE(0, 0);

    for (int t = 0; t < 32; ++t) {
        const int cur = t & 1;
        __syncthreads();                      // buf[cur] ready; prev reads done
        if (t < 31) STAGE(cur ^ 1, t + 1);    // prefetch hides under compute
        const char* Ks = smem + cur * 16384;
        const char* Vs = Ks + 8192;

        // K fragments: A-operand, row = key (d-chunked layout, conflict-free)
        bf16x8 kf0[4], kf1[4];
#pragma unroll
        for (int m = 0; m < 4; ++m) {
            kf0[m] = *(const bf16x8*)(Ks + m * 2048 + l31 * 32 + hi * 16);
            kf1[m] = *(const bf16x8*)(Ks + m * 2048 + (32 + l31) * 32 + hi * 16);
        }

        // ---- coltile 0: S^T = K·Q^T (exp2 domain) ----
        f32x16 s0 = zero16(), s1 = zero16();
        __builtin_amdgcn_s_setprio(1);
#pragma unroll
        for (int m = 0; m < 4; ++m) s0 = MFMA32(kf0[m], qf0[m], s0);
#pragma unroll
        for (int m = 0; m < 4; ++m) s1 = MFMA32(kf1[m], qf0[m], s1);
        __builtin_amdgcn_s_setprio(0);
        {
            float mx = fmaxf(s0[0], s1[0]);
#pragma unroll
            for (int i = 1; i < 16; ++i) mx = fmaxf(mx, fmaxf(s0[i], s1[i]));
            mx = fmaxf(mx, __shfl_xor(mx, 32, 64));
            if (!__all(mx <= mr0 + 8.0f)) {     // defer-max (T13)
                float mn = fmaxf(mr0, mx);
                float al = exp2_raw(mr0 - mn);
                o00 *= al; o01 *= al; fa0 *= al; mr0 = mn;
            }
        }
        u32x4 pk0[4];
#pragma unroll
        for (int m = 0; m < 4; ++m) {
            pk0[m].x = pkbf16(exp2_raw(s0[4 * m] - mr0), exp2_raw(s0[4 * m + 1] - mr0));
            pk0[m].y = pkbf16(exp2_raw(s0[4 * m + 2] - mr0), exp2_raw(s0[4 * m + 3] - mr0));
            pk0[m].z = pkbf16(exp2_raw(s1[4 * m] - mr0), exp2_raw(s1[4 * m + 1] - mr0));
            pk0[m].w = pkbf16(exp2_raw(s1[4 * m + 2] - mr0), exp2_raw(s1[4 * m + 3] - mr0));
        }

        // flag A-row (only lanes with l31==0 carry data; rest zero)
        bf16x8 ff[4];
#pragma unroll
        for (int m = 0; m < 4; ++m) ff[m] = zero8();
        if (l31 == 0) {
#pragma unroll
            for (int m = 0; m < 4; ++m)
                ff[m] = *(const bf16x8*)(Fg + t * 64 + m * 16 + hi * 8);
        }

        // ---- coltile 1 ----
        s0 = zero16(); s1 = zero16();
        __builtin_amdgcn_s_setprio(1);
#pragma unroll
        for (int m = 0; m < 4; ++m) s0 = MFMA32(kf0[m], qf1[m], s0);
#pragma unroll
        for (int m = 0; m < 4; ++m) s1 = MFMA32(kf1[m], qf1[m], s1);
        __builtin_amdgcn_s_setprio(0);
        {
            float mx = fmaxf(s0[0], s1[0]);
#pragma unroll
            for (int i = 1; i < 16; ++i) mx = fmaxf(mx, fmaxf(s0[i], s1[i]));
            mx = fmaxf(mx, __shfl_xor(mx, 32, 64));
            if (!__all(mx <= mr1 + 8.0f)) {
                float mn = fmaxf(mr1, mx);
                float al = exp2_raw(mr1 - mn);
                o10 *= al; o11 *= al; fa1 *= al; mr1 = mn;
            }
        }
        u32x4 pk1[4];
#pragma unroll
        for (int m = 0; m < 4; ++m) {
            pk1[m].x = pkbf16(exp2_raw(s0[4 * m] - mr1), exp2_raw(s0[4 * m + 1] - mr1));
            pk1[m].y = pkbf16(exp2_raw(s0[4 * m + 2] - mr1), exp2_raw(s0[4 * m + 3] - mr1));
            pk1[m].z = pkbf16(exp2_raw(s1[4 * m] - mr1), exp2_raw(s1[4 * m + 1] - mr1));
            pk1[m].w = pkbf16(exp2_raw(s1[4 * m + 2] - mr1), exp2_raw(s1[4 * m + 3] - mr1));
        }

        // ---- PV + denominator ----
        __builtin_amdgcn_s_setprio(1);
#pragma unroll
        for (int m = 0; m < 4; ++m) {
            bf16x8 vf0 = *(const bf16x8*)(Vs + m * 2048 + l31 * 32 + hi * 16);
            bf16x8 vf1 = *(const bf16x8*)(Vs + m * 2048 + (32 + l31) * 32 + hi * 16);
            bf16x8 p0 = __builtin_bit_cast(bf16x8, pk0[m]);
            bf16x8 p1 = __builtin_bit_cast(bf16x8, pk1[m]);
            o00 = MFMA32(vf0, p0, o00);
            o01 = MFMA32(vf1, p0, o01);
            o10 = MFMA32(vf0, p1, o10);
            o11 = MFMA32(vf1, p1, o11);
            fa0 = MFMA32(ff[m], p0, fa0);
            fa1 = MFMA32(ff[m], p1, fa1);
        }
        __builtin_amdgcn_s_setprio(0);
    }

    // ---- epilogue: denom = flag-acc row 0, transpose via LDS, store ----
    __syncthreads();
    float* osm = (float*)smem + wv * 2080;  // 32 x 65 f32 per wave
    const size_t obase = ((size_t)b * 2048 + qt * 256 + wv * 64) * 1024 + h * 64 + l;
    {
        const float inv = 1.0f / __shfl(fa0[0], l31, 64);
#pragma unroll
        for (int r = 0; r < 16; ++r) {
            const int d = (r & 3) + 8 * (r >> 2) + 4 * hi;
            osm[l31 * 65 + d] = o00[r] * inv;
            osm[l31 * 65 + d + 32] = o01[r] * inv;
        }
        lds_fence();
#pragma unroll
        for (int qi = 0; qi < 32; ++qi)
            out[obase + (size_t)qi * 1024] = osm[qi * 65 + l];
        lds_fence();
    }
    {
        const float inv = 1.0f / __shfl(fa1[0], l31, 64);
#pragma unroll
        for (int r = 0; r < 16; ++r) {
            const int d = (r & 3) + 8 * (r >> 2) + 4 * hi;
            osm[l31 * 65 + d] = o10[r] * inv;
            osm[l31 * 65 + d + 32] = o11[r] * inv;
        }
        lds_fence();
#pragma unroll
        for (int qi = 0; qi < 32; ++qi)
            out[obase + (size_t)(32 + qi) * 1024] = osm[qi * 65 + l];
    }
}

// ---------------------------------------------------------------------------
extern "C" void kernel_launch(void* const* d_in, const int* in_sizes, int n_in,
                              void* d_out, int out_size, void* d_ws, size_t ws_size,
                              hipStream_t stream) {
    const float* tokens = (const float*)d_in[0];
    // d_in[1] = sen : DEAD, d_in[3] = W2 : DEAD
    const float* W1 = (const float*)d_in[2];
    const int* mask = (const int*)d_in[4];
    float* out = (float*)d_out;

    char* w = (char*)d_ws;
    __bf16* tokbf = (__bf16*)(w + 0);           // 16,777,216 B
    __bf16* w1t   = (__bf16*)(w + 16777216);    //  6,291,456 B
    __bf16* qarr  = (__bf16*)(w + 23068672);    // 16,777,216 B
    __bf16* karr  = (__bf16*)(w + 39845888);    // 16,777,216 B
    __bf16* vtar  = (__bf16*)(w + 56623104);    // 16,777,216 B (slot-permuted)
    __bf16* flagb = (__bf16*)(w + 73400320);    //     16,384 B (orig order)
    __bf16* flagp = (__bf16*)(w + 73416704);    //     16,384 B (slot-permuted)

    k_cvt_tok<<<8192, 256, 0, stream>>>(tokens, mask, tokbf, flagb, flagp);
    k_w1t<<<3072, 256, 0, stream>>>(W1, w1t);
    k_gemm_qkv<<<1536, 256, 0, stream>>>(tokbf, w1t, flagb, qarr, karr, vtar);
    k_attn<<<512, 256, 0, stream>>>(qarr, karr, vtar, flagp, out);
}